// Round 10
// baseline (298.979 us; speedup 1.0000x reference)
//
#include <hip/hip_runtime.h>
#include <math.h>

#define NN 50000
#define NE 800000
#define IN_CH 10
#define NEGS 0.2f
#define LNEPS 1e-5f
#define LOG2E 1.4426950408889634f
#define P1_BLOCKS 12500           // NN/4 proj1 blocks in the fused proj1+rank kernel
#define RK_BLOCKS 782             // ceil(NE/4/256) rank blocks
#define SCAN_E 1024               // elements per scan block
#define NB 49                     // ceil(NN / SCAN_E)
#define DEGS 16                   // deg counter stride (ints): 1 counter per 64B line

typedef float f2 __attribute__((ext_vector_type(2)));

__device__ __forceinline__ f2 pkfma(f2 a, f2 b, f2 c) {
    return __builtin_elementwise_fma(a, b, c);
}
__device__ __forceinline__ float red16g(float v) {   // sum within aligned 16-lane group
    v += __shfl_xor(v, 1);  v += __shfl_xor(v, 2);
    v += __shfl_xor(v, 4);  v += __shfl_xor(v, 8);
    return v;
}
__device__ __forceinline__ float red32g(float v) {   // sum within aligned 32-lane group
    v = red16g(v); v += __shfl_xor(v, 16);
    return v;
}

// bf16 pack/unpack: RTNE encode, 1-op decode (bf16 pair per dword)
__device__ __forceinline__ unsigned pack_bf16(float a, float b) {
    unsigned ua = __float_as_uint(a);
    unsigned ub = __float_as_uint(b);
    ua = (ua + 0x7FFFu + ((ua >> 16) & 1u)) >> 16;
    ub = (ub + 0x7FFFu + ((ub >> 16) & 1u)) & 0xFFFF0000u;
    return ua | ub;
}
__device__ __forceinline__ float bf_lo(unsigned d) { return __uint_as_float(d << 16); }
__device__ __forceinline__ float bf_hi(unsigned d) { return __uint_as_float(d & 0xFFFF0000u); }

// ---------- fused proj1 + rank ----------
// deg counters padded to 1 per 64B cache line: 800k random atomics spread over
// 50000 lines (16 ops/line) instead of 3125 (256 ops/line) — avoids per-line
// serialization at the coherence point.
__global__ __launch_bounds__(256) void k_proj1_rank(
    const float* __restrict__ x, const float* __restrict__ Wl,
    const float* __restrict__ Wr, float* __restrict__ xl, unsigned* __restrict__ xrb,
    const int* __restrict__ ei, int* __restrict__ deg, int* __restrict__ rank) {
    int bI = blockIdx.x;
    if (bI < P1_BLOCKS) {
        int lane = threadIdx.x & 63;
        int n = bI * 4 + (threadIdx.x >> 6);
        int c0 = lane * 2;
        float al0 = 0.f, al1 = 0.f, ar0 = 0.f, ar1 = 0.f;
#pragma unroll
        for (int k = 0; k < IN_CH; ++k) {
            float xv = x[n * IN_CH + k];
            al0 = fmaf(xv, Wl[k * 128 + c0], al0);
            al1 = fmaf(xv, Wl[k * 128 + c0 + 1], al1);
            ar0 = fmaf(xv, Wr[k * 128 + c0], ar0);
            ar1 = fmaf(xv, Wr[k * 128 + c0 + 1], ar1);
        }
        *(float2*)&xl[(size_t)n * 128 + c0] = make_float2(al0, al1);
        xrb[(size_t)n * 64 + lane] = pack_bf16(ar0, ar1);
    } else {
        int e0 = ((bI - P1_BLOCKS) * 256 + threadIdx.x) * 4;
        if (e0 >= NE) return;
        int4 d4 = *(const int4*)(ei + NE + e0);
        int4 r;
        r.x = atomicAdd(&deg[d4.x * DEGS], 1);
        r.y = atomicAdd(&deg[d4.y * DEGS], 1);
        r.z = atomicAdd(&deg[d4.z * DEGS], 1);
        r.w = atomicAdd(&deg[d4.w * DEGS], 1);
        *(int4*)(rank + e0) = r;
    }
}

// ---------- hierarchical scan (49 blocks + add pass) ----------
__global__ __launch_bounds__(256) void k_scan_block(
    const int* __restrict__ deg, int* __restrict__ rowstart, int* __restrict__ partial) {
    __shared__ int sh[256];
    int t = threadIdx.x;
    int base = blockIdx.x * SCAN_E + t * 4;
    int d0 = 0, d1 = 0, d2 = 0, d3 = 0;
    if (base + 0 < NN) d0 = deg[(base + 0) * DEGS];
    if (base + 1 < NN) d1 = deg[(base + 1) * DEGS];
    if (base + 2 < NN) d2 = deg[(base + 2) * DEGS];
    if (base + 3 < NN) d3 = deg[(base + 3) * DEGS];
    int mysum = d0 + d1 + d2 + d3;
    sh[t] = mysum;
    __syncthreads();
    for (int off = 1; off < 256; off <<= 1) {
        int v = (t >= off) ? sh[t - off] : 0;
        __syncthreads();
        sh[t] += v;
        __syncthreads();
    }
    int ex = sh[t] - mysum;
    if (base + 0 < NN) rowstart[base + 0] = ex;
    if (base + 1 < NN) rowstart[base + 1] = ex + d0;
    if (base + 2 < NN) rowstart[base + 2] = ex + d0 + d1;
    if (base + 3 < NN) rowstart[base + 3] = ex + d0 + d1 + d2;
    if (t == 255) partial[blockIdx.x] = sh[255];
}

__global__ __launch_bounds__(256) void k_scan_add(
    const int* __restrict__ partial, int* __restrict__ rowstart) {
    __shared__ int off;
    int t = threadIdx.x, bI = blockIdx.x;
    if (t == 0) {
        int s = 0;
        for (int k = 0; k < bI; ++k) s += partial[k];
        off = s;
    }
    __syncthreads();
    int base = bI * SCAN_E + t * 4;
#pragma unroll
    for (int i = 0; i < 4; ++i) {
        int idx = base + i;
        if (idx < NN) rowstart[idx] += off;
    }
    if (bI == 0 && t == 0) rowstart[NN] = NE;
}

// ---------- scatter: p = rowstart[d] + rank[e]; no atomics ----------
__global__ __launch_bounds__(256) void k_scatter(
    const int* __restrict__ ei, const float* __restrict__ ea,
    const int* __restrict__ rowstart, const int* __restrict__ rank,
    long long* __restrict__ cpack) {
    int e0 = (blockIdx.x * 256 + threadIdx.x) * 4;
    if (e0 >= NE) return;
    int4 d4 = *(const int4*)(ei + NE + e0);
    int4 s4 = *(const int4*)(ei + e0);
    float4 a4 = *(const float4*)(ea + e0);
    int4 r4 = *(const int4*)(rank + e0);
    int p0 = rowstart[d4.x] + r4.x;
    int p1 = rowstart[d4.y] + r4.y;
    int p2 = rowstart[d4.z] + r4.z;
    int p3 = rowstart[d4.w] + r4.w;
    // {src, ea} little-endian == int2{x=src, y=ea}
    cpack[p0] = ((long long)(unsigned)__float_as_int(a4.x) << 32) | (unsigned)s4.x;
    cpack[p1] = ((long long)(unsigned)__float_as_int(a4.y) << 32) | (unsigned)s4.y;
    cpack[p2] = ((long long)(unsigned)__float_as_int(a4.z) << 32) | (unsigned)s4.z;
    cpack[p3] = ((long long)(unsigned)__float_as_int(a4.w) << 32) | (unsigned)s4.w;
}

// ---------- xl2|xr2b = h1 @ [W2l|W2r] — LDS-tiled register-blocked fp32 GEMM ----------
__global__ __launch_bounds__(256) void k_proj2(
    const float* __restrict__ h1, const float* __restrict__ Wl,
    const float* __restrict__ Wr, float* __restrict__ xl2, unsigned* __restrict__ xr2b) {
    __shared__ float sh_h[64][36];    // +4 pad
    __shared__ float sh_w[32][128];
    int t = threadIdx.x;
    int cg = t & 15, ng = t >> 4;
    int c0 = cg * 8;
    int nb = blockIdx.x * 64;
    float acc[4][8];
#pragma unroll
    for (int j = 0; j < 4; ++j)
#pragma unroll
        for (int i = 0; i < 8; ++i) acc[j][i] = 0.f;

    for (int kc = 0; kc < 128; kc += 32) {
#pragma unroll
        for (int i = 0; i < 2; ++i) {
            int fi = t + i * 256;
            int nl = fi >> 3, kq = fi & 7;
            int n = nb + nl;
            float4 v = make_float4(0.f, 0.f, 0.f, 0.f);
            if (n < NN) v = *(const float4*)&h1[(size_t)n * 128 + kc + kq * 4];
            *(float4*)&sh_h[nl][kq * 4] = v;
        }
#pragma unroll
        for (int i = 0; i < 4; ++i) {
            int fi = t + i * 256;
            int kl = fi >> 5, col = (fi & 31) * 4;
            const float* src = (col < 64) ? &Wl[(size_t)(kc + kl) * 64 + col]
                                          : &Wr[(size_t)(kc + kl) * 64 + col - 64];
            *(float4*)&sh_w[kl][col] = *(const float4*)src;
        }
        __syncthreads();
#pragma unroll
        for (int kl = 0; kl < 32; kl += 4) {
            float4 hv[4];
#pragma unroll
            for (int j = 0; j < 4; ++j) hv[j] = *(const float4*)&sh_h[ng + j * 16][kl];
#pragma unroll
            for (int kk = 0; kk < 4; ++kk) {
                float4 wa = *(const float4*)&sh_w[kl + kk][c0];
                float4 wb = *(const float4*)&sh_w[kl + kk][c0 + 4];
#pragma unroll
                for (int j = 0; j < 4; ++j) {
                    float hs = kk == 0 ? hv[j].x : kk == 1 ? hv[j].y : kk == 2 ? hv[j].z : hv[j].w;
                    acc[j][0] = fmaf(hs, wa.x, acc[j][0]);
                    acc[j][1] = fmaf(hs, wa.y, acc[j][1]);
                    acc[j][2] = fmaf(hs, wa.z, acc[j][2]);
                    acc[j][3] = fmaf(hs, wa.w, acc[j][3]);
                    acc[j][4] = fmaf(hs, wb.x, acc[j][4]);
                    acc[j][5] = fmaf(hs, wb.y, acc[j][5]);
                    acc[j][6] = fmaf(hs, wb.z, acc[j][6]);
                    acc[j][7] = fmaf(hs, wb.w, acc[j][7]);
                }
            }
        }
        __syncthreads();
    }
    if (cg < 8) {
#pragma unroll
        for (int j = 0; j < 4; ++j) {
            int n = nb + ng + j * 16;
            if (n < NN) {
                *(float4*)&xl2[(size_t)n * 64 + c0] =
                    make_float4(acc[j][0], acc[j][1], acc[j][2], acc[j][3]);
                *(float4*)&xl2[(size_t)n * 64 + c0 + 4] =
                    make_float4(acc[j][4], acc[j][5], acc[j][6], acc[j][7]);
            }
        }
    } else {
        int cc = c0 - 64;
#pragma unroll
        for (int j = 0; j < 4; ++j) {
            int n = nb + ng + j * 16;
            if (n < NN) {
                uint4 pk;
                pk.x = pack_bf16(acc[j][0], acc[j][1]);
                pk.y = pack_bf16(acc[j][2], acc[j][3]);
                pk.z = pack_bf16(acc[j][4], acc[j][5]);
                pk.w = pack_bf16(acc[j][6], acc[j][7]);
                *(uint4*)&xr2b[(size_t)n * 32 + (cc >> 1)] = pk;
            }
        }
    }
}

// ---------- fused per-node GATv2 layers ----------
// att·lrelu(u) folded as (0.6att)·u + (0.4att)·|u| (abs = free VOP3 modifier);
// log2e folded so softmax weight = exp2(dot). u-compute/accumulate via v_pk_fma_f32.

__device__ __forceinline__ void edge1_step(
    const int2* __restrict__ cpack, const unsigned char* __restrict__ xrb, int p, int l,
    const f2& xl01, const f2& xl23, const f2& We01, const f2& We23,
    const f2& at6a, const f2& at6b, const f2& at4a, const f2& at4b,
    f2& acc01, f2& acc23, float& den, bool tail, int pmax) {
    bool valid = !tail || (p <= pmax);
    int2 pk = cpack[valid ? p : pmax];
    float eav = __int_as_float(pk.y);
    unsigned off = (unsigned)pk.x * 256u + (unsigned)(l * 8);
    uint2 dw = *(const uint2*)(xrb + off);
    f2 x01, x23;
    x01.x = bf_lo(dw.x); x01.y = bf_hi(dw.x);
    x23.x = bf_lo(dw.y); x23.y = bf_hi(dw.y);
    f2 ev = {eav, eav};
    f2 u01 = pkfma(ev, We01, xl01) + x01;
    f2 u23 = pkfma(ev, We23, xl23) + x23;
    float dot = fmaf(at6a.x, u01.x, at4a.x * fabsf(u01.x));
    dot = fmaf(at6a.y, u01.y, fmaf(at4a.y, fabsf(u01.y), dot));
    dot = fmaf(at6b.x, u23.x, fmaf(at4b.x, fabsf(u23.x), dot));
    dot = fmaf(at6b.y, u23.y, fmaf(at4b.y, fabsf(u23.y), dot));
    dot += __shfl_xor(dot, 1);
    dot += __shfl_xor(dot, 2);
    dot += __shfl_xor(dot, 4);          // head logit (8-lane group)
    float el = exp2f(dot);              // max-shift skipped: alpha invariant, |logit| small
    if (tail && !valid) el = 0.f;
    den += el;
    f2 el2 = {el, el};
    acc01 = pkfma(el2, x01, acc01);
    acc23 = pkfma(el2, x23, acc23);
}

// layer 1: wave per node; 4 edge slots x 2 halves = 8 bf16 gathers in flight.
__global__ __launch_bounds__(256) void k_fused1(
    const int* __restrict__ rs, const int2* __restrict__ cpack,
    const float* __restrict__ xl, const unsigned char* __restrict__ xrb,
    const float* __restrict__ We, const float* __restrict__ att,
    const float* __restrict__ bias, const float* __restrict__ g,
    const float* __restrict__ b, float* __restrict__ h1) {
    int lane = threadIdx.x & 63;
    int n = blockIdx.x * 4 + (threadIdx.x >> 6);
    if (n >= NN) return;
    int half = lane >> 5;
    int l = lane & 31;
    int c0 = l * 4;
    float4 xldf = *(const float4*)&xl[(size_t)n * 128 + c0];
    float4 Wef = *(const float4*)&We[c0];
    float4 atv = *(const float4*)&att[c0];
    f2 xl01 = {xldf.x, xldf.y}, xl23 = {xldf.z, xldf.w};
    f2 We01 = {Wef.x, Wef.y}, We23 = {Wef.z, Wef.w};
    f2 at6a = {atv.x * (0.6f * LOG2E), atv.y * (0.6f * LOG2E)};
    f2 at6b = {atv.z * (0.6f * LOG2E), atv.w * (0.6f * LOG2E)};
    f2 at4a = {atv.x * (0.4f * LOG2E), atv.y * (0.4f * LOG2E)};
    f2 at4b = {atv.z * (0.4f * LOG2E), atv.w * (0.4f * LOG2E)};
    int beg = rs[n], end = rs[n + 1];
    int cnt = end - beg;
    int pfull = beg + (cnt & ~7);
    f2 a01[2] = {{0.f, 0.f}, {0.f, 0.f}};
    f2 a23[2] = {{0.f, 0.f}, {0.f, 0.f}};
    float den[2] = {0.f, 0.f};
    for (int p0 = beg; p0 < pfull; p0 += 8) {
#pragma unroll
        for (int s = 0; s < 4; ++s)
            edge1_step(cpack, xrb, p0 + s * 2 + half, l, xl01, xl23, We01, We23,
                       at6a, at6b, at4a, at4b, a01[s & 1], a23[s & 1], den[s & 1],
                       false, 0);
    }
    if (cnt & 7) {
#pragma unroll
        for (int s = 0; s < 4; ++s)
            edge1_step(cpack, xrb, pfull + s * 2 + half, l, xl01, xl23, We01, We23,
                       at6a, at6b, at4a, at4b, a01[s & 1], a23[s & 1], den[s & 1],
                       true, end - 1);
    }
    f2 s01 = a01[0] + a01[1];
    f2 s23 = a23[0] + a23[1];
    float den0 = den[0] + den[1];
    s01.x += __shfl_xor(s01.x, 32);
    s01.y += __shfl_xor(s01.y, 32);
    s23.x += __shfl_xor(s23.x, 32);
    s23.y += __shfl_xor(s23.y, 32);
    den0 += __shfl_xor(den0, 32);
    float inv = den0 > 0.f ? 1.f / den0 : 0.f;
    float4 bv = *(const float4*)&bias[c0];
    float a0 = s01.x * inv + bv.x;
    float a1 = s01.y * inv + bv.y;
    float a2 = s23.x * inv + bv.z;
    float a3 = s23.y * inv + bv.w;
    float mu = red32g(a0 + a1 + a2 + a3) * (1.f / 128.f);
    float d0 = a0 - mu, d1 = a1 - mu, d2 = a2 - mu, d3 = a3 - mu;
    float var = red32g(d0 * d0 + d1 * d1 + d2 * d2 + d3 * d3) * (1.f / 128.f);
    float rsq = rsqrtf(var + LNEPS);
    float4 gv = *(const float4*)&g[c0];
    float4 bb = *(const float4*)&b[c0];
    float o0 = d0 * rsq * gv.x + bb.x;
    float o1 = d1 * rsq * gv.y + bb.y;
    float o2 = d2 * rsq * gv.z + bb.z;
    float o3 = d3 * rsq * gv.w + bb.w;
    o0 = o0 > 0.f ? o0 : __expf(o0) - 1.f;
    o1 = o1 > 0.f ? o1 : __expf(o1) - 1.f;
    o2 = o2 > 0.f ? o2 : __expf(o2) - 1.f;
    o3 = o3 > 0.f ? o3 : __expf(o3) - 1.f;
    if (half == 0)
        *(float4*)&h1[(size_t)n * 128 + c0] = make_float4(o0, o1, o2, o3);
}

__device__ __forceinline__ void edge2_step(
    const int2* __restrict__ cpack, const unsigned char* __restrict__ xr2b, int p, int l,
    const f2& xl01, const f2& xl23, const f2& We01, const f2& We23,
    const f2& at6a, const f2& at6b, const f2& at4a, const f2& at4b,
    f2& acc01, f2& acc23, float& den, bool tail, int pmax) {
    bool valid = !tail || (p <= pmax);
    int2 pk = cpack[valid ? p : pmax];
    float eav = __int_as_float(pk.y);
    unsigned off = (unsigned)pk.x * 128u + (unsigned)(l * 8);
    uint2 dw = *(const uint2*)(xr2b + off);
    f2 x01, x23;
    x01.x = bf_lo(dw.x); x01.y = bf_hi(dw.x);
    x23.x = bf_lo(dw.y); x23.y = bf_hi(dw.y);
    f2 ev = {eav, eav};
    f2 u01 = pkfma(ev, We01, xl01) + x01;
    f2 u23 = pkfma(ev, We23, xl23) + x23;
    float dot = fmaf(at6a.x, u01.x, at4a.x * fabsf(u01.x));
    dot = fmaf(at6a.y, u01.y, fmaf(at4a.y, fabsf(u01.y), dot));
    dot = fmaf(at6b.x, u23.x, fmaf(at4b.x, fabsf(u23.x), dot));
    dot = fmaf(at6b.y, u23.y, fmaf(at4b.y, fabsf(u23.y), dot));
    dot += __shfl_xor(dot, 1);
    dot += __shfl_xor(dot, 2);
    dot += __shfl_xor(dot, 4);
    dot += __shfl_xor(dot, 8);          // logit (16-lane group)
    float el = exp2f(dot);
    if (tail && !valid) el = 0.f;
    den += el;
    f2 el2 = {el, el};
    acc01 = pkfma(el2, x01, acc01);
    acc23 = pkfma(el2, x23, acc23);
}

// layer 2: wave per node; 4 edge groups x 2 slots = 8 bf16 gathers in flight; single head
__global__ __launch_bounds__(256) void k_fused2(
    const int* __restrict__ rs, const int2* __restrict__ cpack,
    const float* __restrict__ xl2, const unsigned char* __restrict__ xr2b,
    const float* __restrict__ We, const float* __restrict__ att,
    const float* __restrict__ bias, const float* __restrict__ g,
    const float* __restrict__ b, float* __restrict__ out) {
    int lane = threadIdx.x & 63;
    int n = blockIdx.x * 4 + (threadIdx.x >> 6);
    if (n >= NN) return;
    int grp = lane >> 4;
    int l = lane & 15;
    int c0 = l * 4;
    float4 xldf = *(const float4*)&xl2[(size_t)n * 64 + c0];
    float4 Wef = *(const float4*)&We[c0];
    float4 atv = *(const float4*)&att[c0];
    f2 xl01 = {xldf.x, xldf.y}, xl23 = {xldf.z, xldf.w};
    f2 We01 = {Wef.x, Wef.y}, We23 = {Wef.z, Wef.w};
    f2 at6a = {atv.x * (0.6f * LOG2E), atv.y * (0.6f * LOG2E)};
    f2 at6b = {atv.z * (0.6f * LOG2E), atv.w * (0.6f * LOG2E)};
    f2 at4a = {atv.x * (0.4f * LOG2E), atv.y * (0.4f * LOG2E)};
    f2 at4b = {atv.z * (0.4f * LOG2E), atv.w * (0.4f * LOG2E)};
    int beg = rs[n], end = rs[n + 1];
    int cnt = end - beg;
    int pfull = beg + (cnt & ~7);
    f2 a01[2] = {{0.f, 0.f}, {0.f, 0.f}};
    f2 a23[2] = {{0.f, 0.f}, {0.f, 0.f}};
    float den[2] = {0.f, 0.f};
    for (int p0 = beg; p0 < pfull; p0 += 8) {
#pragma unroll
        for (int s = 0; s < 2; ++s)
            edge2_step(cpack, xr2b, p0 + s * 4 + grp, l, xl01, xl23, We01, We23,
                       at6a, at6b, at4a, at4b, a01[s], a23[s], den[s], false, 0);
    }
    if (cnt & 7) {
#pragma unroll
        for (int s = 0; s < 2; ++s)
            edge2_step(cpack, xr2b, pfull + s * 4 + grp, l, xl01, xl23, We01, We23,
                       at6a, at6b, at4a, at4b, a01[s], a23[s], den[s], true, end - 1);
    }
    f2 s01 = a01[0] + a01[1];
    f2 s23 = a23[0] + a23[1];
    float den0 = den[0] + den[1];
    s01.x += __shfl_xor(s01.x, 16); s01.x += __shfl_xor(s01.x, 32);
    s01.y += __shfl_xor(s01.y, 16); s01.y += __shfl_xor(s01.y, 32);
    s23.x += __shfl_xor(s23.x, 16); s23.x += __shfl_xor(s23.x, 32);
    s23.y += __shfl_xor(s23.y, 16); s23.y += __shfl_xor(s23.y, 32);
    den0 += __shfl_xor(den0, 16); den0 += __shfl_xor(den0, 32);
    float inv = den0 > 0.f ? 1.f / den0 : 0.f;
    float4 bv = *(const float4*)&bias[c0];
    float a0 = s01.x * inv + bv.x;
    float a1 = s01.y * inv + bv.y;
    float a2 = s23.x * inv + bv.z;
    float a3 = s23.y * inv + bv.w;
    float mu = red16g(a0 + a1 + a2 + a3) * (1.f / 64.f);
    float d0 = a0 - mu, d1 = a1 - mu, d2 = a2 - mu, d3 = a3 - mu;
    float var = red16g(d0 * d0 + d1 * d1 + d2 * d2 + d3 * d3) * (1.f / 64.f);
    float rsq = rsqrtf(var + LNEPS);
    float4 gv = *(const float4*)&g[c0];
    float4 bb = *(const float4*)&b[c0];
    float o0 = d0 * rsq * gv.x + bb.x;
    float o1 = d1 * rsq * gv.y + bb.y;
    float o2 = d2 * rsq * gv.z + bb.z;
    float o3 = d3 * rsq * gv.w + bb.w;
    o0 = o0 > 0.f ? o0 : __expf(o0) - 1.f;
    o1 = o1 > 0.f ? o1 : __expf(o1) - 1.f;
    o2 = o2 > 0.f ? o2 : __expf(o2) - 1.f;
    o3 = o3 > 0.f ? o3 : __expf(o3) - 1.f;
    if (grp == 0)
        *(float4*)&out[(size_t)n * 64 + c0] = make_float4(o0, o1, o2, o3);
}

extern "C" void kernel_launch(void* const* d_in, const int* in_sizes, int n_in,
                              void* d_out, int out_size, void* d_ws, size_t ws_size,
                              hipStream_t stream) {
    const float* x    = (const float*)d_in[0];
    const float* ea   = (const float*)d_in[1];
    const float* W1l  = (const float*)d_in[2];
    const float* W1r  = (const float*)d_in[3];
    const float* W1e  = (const float*)d_in[4];
    const float* att1 = (const float*)d_in[5];
    const float* b1   = (const float*)d_in[6];
    const float* ln1g = (const float*)d_in[7];
    const float* ln1b = (const float*)d_in[8];
    const float* W2l  = (const float*)d_in[9];
    const float* W2r  = (const float*)d_in[10];
    const float* W2e  = (const float*)d_in[11];
    const float* att2 = (const float*)d_in[12];
    const float* b2   = (const float*)d_in[13];
    const float* ln2g = (const float*)d_in[14];
    const float* ln2b = (const float*)d_in[15];
    const int*   ei   = (const int*)d_in[16];
    float* out = (float*)d_out;
    float* ws  = (float*)d_ws;

    const size_t A = (size_t)NN * 128;
    float* xl1 = ws;                                   // N*128 f32
    float* h1  = ws + A;                               // N*128 f32
    float* xl2 = ws + 2 * A;                           // N*64 f32
    unsigned* xr1b = (unsigned*)(ws + 2 * A + (size_t)NN * 64);   // N*64 dwords (128 bf16)
    unsigned* xr2b = xr1b + (size_t)NN * 64;           // N*32 dwords (64 bf16)
    long long* cpack = (long long*)(xr2b + (size_t)NN * 32);      // NE x 8B {src, ea}
    int* rank    = (int*)(cpack + (size_t)NE);         // NE
    int* deg     = rank + NE;                          // NN*DEGS (line-padded counters)
    int* rowstart= deg + (size_t)NN * DEGS;            // NN+1
    int* partial = rowstart + NN + 1;                  // NB

    hipMemsetAsync(deg, 0, (size_t)NN * DEGS * sizeof(int), stream);

    k_proj1_rank<<<P1_BLOCKS + RK_BLOCKS, 256, 0, stream>>>(x, W1l, W1r, xl1, xr1b,
                                                            ei, deg, rank);
    k_scan_block<<<NB, 256, 0, stream>>>(deg, rowstart, partial);
    k_scan_add<<<NB, 256, 0, stream>>>(partial, rowstart);
    k_scatter<<<(NE / 4 + 255) / 256, 256, 0, stream>>>(ei, ea, rowstart, rank, cpack);

    k_fused1<<<(NN + 3) / 4, 256, 0, stream>>>(rowstart, (const int2*)cpack, xl1,
                                               (const unsigned char*)xr1b, W1e, att1, b1,
                                               ln1g, ln1b, h1);
    k_proj2<<<(NN + 63) / 64, 256, 0, stream>>>(h1, W2l, W2r, xl2, xr2b);
    k_fused2<<<(NN + 3) / 4, 256, 0, stream>>>(rowstart, (const int2*)cpack, xl2,
                                               (const unsigned char*)xr2b, W2e, att2, b2,
                                               ln2g, ln2b, out);
}

// Round 11
// 274.034 us; speedup vs baseline: 1.0910x; 1.0910x over previous
//
#include <hip/hip_runtime.h>
#include <math.h>

#define NN 50000
#define NE 800000
#define IN_CH 10
#define NEGS 0.2f
#define LNEPS 1e-5f
#define LOG2E 1.4426950408889634f
#define CH_BLOCKS 782             // ceil(NE / 1024) edge-chunk blocks
#define NBUK 196                  // ceil(NN / 256) coarse buckets (dst >> 8)

typedef float f2 __attribute__((ext_vector_type(2)));

__device__ __forceinline__ f2 pkfma(f2 a, f2 b, f2 c) {
    return __builtin_elementwise_fma(a, b, c);
}
__device__ __forceinline__ float red16g(float v) {   // sum within aligned 16-lane group
    v += __shfl_xor(v, 1);  v += __shfl_xor(v, 2);
    v += __shfl_xor(v, 4);  v += __shfl_xor(v, 8);
    return v;
}
__device__ __forceinline__ float red32g(float v) {   // sum within aligned 32-lane group
    v = red16g(v); v += __shfl_xor(v, 16);
    return v;
}

// bf16 pack/unpack: RTNE encode, 1-op decode (bf16 pair per dword)
__device__ __forceinline__ unsigned pack_bf16(float a, float b) {
    unsigned ua = __float_as_uint(a);
    unsigned ub = __float_as_uint(b);
    ua = (ua + 0x7FFFu + ((ua >> 16) & 1u)) >> 16;
    ub = (ub + 0x7FFFu + ((ub >> 16) & 1u)) & 0xFFFF0000u;
    return ua | ub;
}
__device__ __forceinline__ float bf_lo(unsigned d) { return __uint_as_float(d << 16); }
__device__ __forceinline__ float bf_hi(unsigned d) { return __uint_as_float(d & 0xFFFF0000u); }

// ---------- proj1: xl = x@W1l (f32), xrb = bf16(x@W1r) ----------
__global__ __launch_bounds__(256) void k_proj1(
    const float* __restrict__ x, const float* __restrict__ Wl,
    const float* __restrict__ Wr, float* __restrict__ xl, unsigned* __restrict__ xrb) {
    int lane = threadIdx.x & 63;
    int n = blockIdx.x * 4 + (threadIdx.x >> 6);
    if (n >= NN) return;
    int c0 = lane * 2;
    float al0 = 0.f, al1 = 0.f, ar0 = 0.f, ar1 = 0.f;
#pragma unroll
    for (int k = 0; k < IN_CH; ++k) {
        float xv = x[n * IN_CH + k];
        al0 = fmaf(xv, Wl[k * 128 + c0], al0);
        al1 = fmaf(xv, Wl[k * 128 + c0 + 1], al1);
        ar0 = fmaf(xv, Wr[k * 128 + c0], ar0);
        ar1 = fmaf(xv, Wr[k * 128 + c0 + 1], ar1);
    }
    *(float2*)&xl[(size_t)n * 128 + c0] = make_float2(al0, al1);
    xrb[(size_t)n * 64 + lane] = pack_bf16(ar0, ar1);
}

// ---------- atomic-free CSR build: 2-level bucket sort, LDS atomics only ----------

// Pass 1: per-block LDS histogram over 256 coarse buckets (dst>>8)
__global__ __launch_bounds__(256) void k_hist(
    const int* __restrict__ ei, int* __restrict__ bh) {
    __shared__ int h[256];
    int t = threadIdx.x, b = blockIdx.x;
    h[t] = 0;
    __syncthreads();
    int e0 = b * 1024 + t * 4;
    if (e0 < NE) {
        int4 d4 = *(const int4*)(ei + NE + e0);
        atomicAdd(&h[d4.x >> 8], 1);
        atomicAdd(&h[d4.y >> 8], 1);
        atomicAdd(&h[d4.z >> 8], 1);
        atomicAdd(&h[d4.w >> 8], 1);
    }
    __syncthreads();
    bh[b * 256 + t] = h[t];
}

// Per-bucket column prefix over blocks (in-place) + column totals
__global__ __launch_bounds__(256) void k_colscan(
    int* __restrict__ bh, int* __restrict__ coltotal) {
    __shared__ int sh[256];
    int t = threadIdx.x, j = blockIdx.x;
    int v[4];
    int mysum = 0;
#pragma unroll
    for (int i = 0; i < 4; ++i) {
        int r = t * 4 + i;
        v[i] = (r < CH_BLOCKS) ? bh[r * 256 + j] : 0;
        mysum += v[i];
    }
    sh[t] = mysum;
    __syncthreads();
    for (int off = 1; off < 256; off <<= 1) {
        int u = (t >= off) ? sh[t - off] : 0;
        __syncthreads();
        sh[t] += u;
        __syncthreads();
    }
    int ex = sh[t] - mysum;
#pragma unroll
    for (int i = 0; i < 4; ++i) {
        int r = t * 4 + i;
        if (r < CH_BLOCKS) { bh[r * 256 + j] = ex; ex += v[i]; }
    }
    if (t == 255) coltotal[j] = sh[255];
}

// Exclusive scan of 256 bucket totals -> global bucket bases bb[257]
__global__ __launch_bounds__(256) void k_bb(
    const int* __restrict__ coltotal, int* __restrict__ bb) {
    __shared__ int sh[256];
    int t = threadIdx.x;
    int v = coltotal[t];
    sh[t] = v;
    __syncthreads();
    for (int off = 1; off < 256; off <<= 1) {
        int u = (t >= off) ? sh[t - off] : 0;
        __syncthreads();
        sh[t] += u;
        __syncthreads();
    }
    bb[t] = sh[t] - v;
    if (t == 255) bb[256] = sh[255];
}

// Pass 2: scatter edges into coarse buckets; rank via returning LDS atomic
__global__ __launch_bounds__(256) void k_coarse(
    const int* __restrict__ ei, const float* __restrict__ ea,
    const int* __restrict__ bh, const int* __restrict__ bb,
    int2* __restrict__ coarse) {
    __shared__ int h[256];
    __shared__ int lbase[256];
    int t = threadIdx.x, b = blockIdx.x;
    h[t] = 0;
    lbase[t] = bb[t] + bh[b * 256 + t];
    __syncthreads();
    int e0 = b * 1024 + t * 4;
    if (e0 >= NE) return;
    int4 d4 = *(const int4*)(ei + NE + e0);
    int4 s4 = *(const int4*)(ei + e0);
    float4 a4 = *(const float4*)(ea + e0);
    {
        int bk = d4.x >> 8; int r = atomicAdd(&h[bk], 1);
        coarse[lbase[bk] + r] = make_int2(s4.x | ((d4.x & 255) << 16), __float_as_int(a4.x));
    }
    {
        int bk = d4.y >> 8; int r = atomicAdd(&h[bk], 1);
        coarse[lbase[bk] + r] = make_int2(s4.y | ((d4.y & 255) << 16), __float_as_int(a4.y));
    }
    {
        int bk = d4.z >> 8; int r = atomicAdd(&h[bk], 1);
        coarse[lbase[bk] + r] = make_int2(s4.z | ((d4.z & 255) << 16), __float_as_int(a4.z));
    }
    {
        int bk = d4.w >> 8; int r = atomicAdd(&h[bk], 1);
        coarse[lbase[bk] + r] = make_int2(s4.w | ((d4.w & 255) << 16), __float_as_int(a4.w));
    }
}

// Pass 3: one block per bucket — exact per-node CSR within bucket, all in LDS.
// Also writes rowstart directly (global base + in-bucket prefix).
__global__ __launch_bounds__(256) void k_fine(
    const int2* __restrict__ coarse, const int* __restrict__ bb,
    int* __restrict__ rowstart, int2* __restrict__ cpack) {
    __shared__ int cnt[256];
    __shared__ int pfx[256];
    __shared__ int sh[256];
    int t = threadIdx.x, b = blockIdx.x;
    cnt[t] = 0;
    __syncthreads();
    int lo = bb[b], hi = bb[b + 1];
    int ecnt = hi - lo;
    for (int i = t; i < ecnt; i += 256) {
        int dl = (coarse[lo + i].x >> 16) & 255;
        atomicAdd(&cnt[dl], 1);
    }
    __syncthreads();
    int v = cnt[t];
    sh[t] = v;
    __syncthreads();
    for (int off = 1; off < 256; off <<= 1) {
        int u = (t >= off) ? sh[t - off] : 0;
        __syncthreads();
        sh[t] += u;
        __syncthreads();
    }
    pfx[t] = sh[t] - v;   // exclusive in-bucket prefix
    int n0 = b * 256;
    if (n0 + t < NN) rowstart[n0 + t] = lo + (sh[t] - v);
    if (b == 0 && t == 0) rowstart[NN] = NE;
    cnt[t] = 0;
    __syncthreads();
    for (int i = t; i < ecnt; i += 256) {
        int2 c = coarse[lo + i];
        int dl = (c.x >> 16) & 255;
        int r = atomicAdd(&cnt[dl], 1);
        cpack[lo + pfx[dl] + r] = make_int2(c.x & 0xFFFF, c.y);
    }
}

// ---------- xl2|xr2b = h1 @ [W2l|W2r] — LDS-tiled register-blocked fp32 GEMM ----------
__global__ __launch_bounds__(256) void k_proj2(
    const float* __restrict__ h1, const float* __restrict__ Wl,
    const float* __restrict__ Wr, float* __restrict__ xl2, unsigned* __restrict__ xr2b) {
    __shared__ float sh_h[64][36];    // +4 pad
    __shared__ float sh_w[32][128];
    int t = threadIdx.x;
    int cg = t & 15, ng = t >> 4;
    int c0 = cg * 8;
    int nb = blockIdx.x * 64;
    float acc[4][8];
#pragma unroll
    for (int j = 0; j < 4; ++j)
#pragma unroll
        for (int i = 0; i < 8; ++i) acc[j][i] = 0.f;

    for (int kc = 0; kc < 128; kc += 32) {
#pragma unroll
        for (int i = 0; i < 2; ++i) {
            int fi = t + i * 256;
            int nl = fi >> 3, kq = fi & 7;
            int n = nb + nl;
            float4 v = make_float4(0.f, 0.f, 0.f, 0.f);
            if (n < NN) v = *(const float4*)&h1[(size_t)n * 128 + kc + kq * 4];
            *(float4*)&sh_h[nl][kq * 4] = v;
        }
#pragma unroll
        for (int i = 0; i < 4; ++i) {
            int fi = t + i * 256;
            int kl = fi >> 5, col = (fi & 31) * 4;
            const float* src = (col < 64) ? &Wl[(size_t)(kc + kl) * 64 + col]
                                          : &Wr[(size_t)(kc + kl) * 64 + col - 64];
            *(float4*)&sh_w[kl][col] = *(const float4*)src;
        }
        __syncthreads();
#pragma unroll
        for (int kl = 0; kl < 32; kl += 4) {
            float4 hv[4];
#pragma unroll
            for (int j = 0; j < 4; ++j) hv[j] = *(const float4*)&sh_h[ng + j * 16][kl];
#pragma unroll
            for (int kk = 0; kk < 4; ++kk) {
                float4 wa = *(const float4*)&sh_w[kl + kk][c0];
                float4 wb = *(const float4*)&sh_w[kl + kk][c0 + 4];
#pragma unroll
                for (int j = 0; j < 4; ++j) {
                    float hs = kk == 0 ? hv[j].x : kk == 1 ? hv[j].y : kk == 2 ? hv[j].z : hv[j].w;
                    acc[j][0] = fmaf(hs, wa.x, acc[j][0]);
                    acc[j][1] = fmaf(hs, wa.y, acc[j][1]);
                    acc[j][2] = fmaf(hs, wa.z, acc[j][2]);
                    acc[j][3] = fmaf(hs, wa.w, acc[j][3]);
                    acc[j][4] = fmaf(hs, wb.x, acc[j][4]);
                    acc[j][5] = fmaf(hs, wb.y, acc[j][5]);
                    acc[j][6] = fmaf(hs, wb.z, acc[j][6]);
                    acc[j][7] = fmaf(hs, wb.w, acc[j][7]);
                }
            }
        }
        __syncthreads();
    }
    if (cg < 8) {
#pragma unroll
        for (int j = 0; j < 4; ++j) {
            int n = nb + ng + j * 16;
            if (n < NN) {
                *(float4*)&xl2[(size_t)n * 64 + c0] =
                    make_float4(acc[j][0], acc[j][1], acc[j][2], acc[j][3]);
                *(float4*)&xl2[(size_t)n * 64 + c0 + 4] =
                    make_float4(acc[j][4], acc[j][5], acc[j][6], acc[j][7]);
            }
        }
    } else {
        int cc = c0 - 64;
#pragma unroll
        for (int j = 0; j < 4; ++j) {
            int n = nb + ng + j * 16;
            if (n < NN) {
                uint4 pk;
                pk.x = pack_bf16(acc[j][0], acc[j][1]);
                pk.y = pack_bf16(acc[j][2], acc[j][3]);
                pk.z = pack_bf16(acc[j][4], acc[j][5]);
                pk.w = pack_bf16(acc[j][6], acc[j][7]);
                *(uint4*)&xr2b[(size_t)n * 32 + (cc >> 1)] = pk;
            }
        }
    }
}

// ---------- fused per-node GATv2 layers ----------
// att·lrelu(u) folded as (0.6att)·u + (0.4att)·|u| (abs = free VOP3 modifier);
// log2e folded so softmax weight = exp2(dot). u-compute/accumulate via v_pk_fma_f32.

__device__ __forceinline__ void edge1_step(
    const int2* __restrict__ cpack, const unsigned char* __restrict__ xrb, int p, int l,
    const f2& xl01, const f2& xl23, const f2& We01, const f2& We23,
    const f2& at6a, const f2& at6b, const f2& at4a, const f2& at4b,
    f2& acc01, f2& acc23, float& den, bool tail, int pmax) {
    bool valid = !tail || (p <= pmax);
    int2 pk = cpack[valid ? p : pmax];
    float eav = __int_as_float(pk.y);
    unsigned off = (unsigned)pk.x * 256u + (unsigned)(l * 8);
    uint2 dw = *(const uint2*)(xrb + off);
    f2 x01, x23;
    x01.x = bf_lo(dw.x); x01.y = bf_hi(dw.x);
    x23.x = bf_lo(dw.y); x23.y = bf_hi(dw.y);
    f2 ev = {eav, eav};
    f2 u01 = pkfma(ev, We01, xl01) + x01;
    f2 u23 = pkfma(ev, We23, xl23) + x23;
    float dot = fmaf(at6a.x, u01.x, at4a.x * fabsf(u01.x));
    dot = fmaf(at6a.y, u01.y, fmaf(at4a.y, fabsf(u01.y), dot));
    dot = fmaf(at6b.x, u23.x, fmaf(at4b.x, fabsf(u23.x), dot));
    dot = fmaf(at6b.y, u23.y, fmaf(at4b.y, fabsf(u23.y), dot));
    dot += __shfl_xor(dot, 1);
    dot += __shfl_xor(dot, 2);
    dot += __shfl_xor(dot, 4);          // head logit (8-lane group)
    float el = exp2f(dot);              // max-shift skipped: alpha invariant, |logit| small
    if (tail && !valid) el = 0.f;
    den += el;
    f2 el2 = {el, el};
    acc01 = pkfma(el2, x01, acc01);
    acc23 = pkfma(el2, x23, acc23);
}

// layer 1: wave per node; 4 edge slots x 2 halves = 8 bf16 gathers in flight.
__global__ __launch_bounds__(256) void k_fused1(
    const int* __restrict__ rs, const int2* __restrict__ cpack,
    const float* __restrict__ xl, const unsigned char* __restrict__ xrb,
    const float* __restrict__ We, const float* __restrict__ att,
    const float* __restrict__ bias, const float* __restrict__ g,
    const float* __restrict__ b, float* __restrict__ h1) {
    int lane = threadIdx.x & 63;
    int n = blockIdx.x * 4 + (threadIdx.x >> 6);
    if (n >= NN) return;
    int half = lane >> 5;
    int l = lane & 31;
    int c0 = l * 4;
    float4 xldf = *(const float4*)&xl[(size_t)n * 128 + c0];
    float4 Wef = *(const float4*)&We[c0];
    float4 atv = *(const float4*)&att[c0];
    f2 xl01 = {xldf.x, xldf.y}, xl23 = {xldf.z, xldf.w};
    f2 We01 = {Wef.x, Wef.y}, We23 = {Wef.z, Wef.w};
    f2 at6a = {atv.x * (0.6f * LOG2E), atv.y * (0.6f * LOG2E)};
    f2 at6b = {atv.z * (0.6f * LOG2E), atv.w * (0.6f * LOG2E)};
    f2 at4a = {atv.x * (0.4f * LOG2E), atv.y * (0.4f * LOG2E)};
    f2 at4b = {atv.z * (0.4f * LOG2E), atv.w * (0.4f * LOG2E)};
    int beg = rs[n], end = rs[n + 1];
    int cnt = end - beg;
    int pfull = beg + (cnt & ~7);
    f2 a01[2] = {{0.f, 0.f}, {0.f, 0.f}};
    f2 a23[2] = {{0.f, 0.f}, {0.f, 0.f}};
    float den[2] = {0.f, 0.f};
    for (int p0 = beg; p0 < pfull; p0 += 8) {
#pragma unroll
        for (int s = 0; s < 4; ++s)
            edge1_step(cpack, xrb, p0 + s * 2 + half, l, xl01, xl23, We01, We23,
                       at6a, at6b, at4a, at4b, a01[s & 1], a23[s & 1], den[s & 1],
                       false, 0);
    }
    if (cnt & 7) {
#pragma unroll
        for (int s = 0; s < 4; ++s)
            edge1_step(cpack, xrb, pfull + s * 2 + half, l, xl01, xl23, We01, We23,
                       at6a, at6b, at4a, at4b, a01[s & 1], a23[s & 1], den[s & 1],
                       true, end - 1);
    }
    f2 s01 = a01[0] + a01[1];
    f2 s23 = a23[0] + a23[1];
    float den0 = den[0] + den[1];
    s01.x += __shfl_xor(s01.x, 32);
    s01.y += __shfl_xor(s01.y, 32);
    s23.x += __shfl_xor(s23.x, 32);
    s23.y += __shfl_xor(s23.y, 32);
    den0 += __shfl_xor(den0, 32);
    float inv = den0 > 0.f ? 1.f / den0 : 0.f;
    float4 bv = *(const float4*)&bias[c0];
    float a0 = s01.x * inv + bv.x;
    float a1 = s01.y * inv + bv.y;
    float a2 = s23.x * inv + bv.z;
    float a3 = s23.y * inv + bv.w;
    float mu = red32g(a0 + a1 + a2 + a3) * (1.f / 128.f);
    float d0 = a0 - mu, d1 = a1 - mu, d2 = a2 - mu, d3 = a3 - mu;
    float var = red32g(d0 * d0 + d1 * d1 + d2 * d2 + d3 * d3) * (1.f / 128.f);
    float rsq = rsqrtf(var + LNEPS);
    float4 gv = *(const float4*)&g[c0];
    float4 bb = *(const float4*)&b[c0];
    float o0 = d0 * rsq * gv.x + bb.x;
    float o1 = d1 * rsq * gv.y + bb.y;
    float o2 = d2 * rsq * gv.z + bb.z;
    float o3 = d3 * rsq * gv.w + bb.w;
    o0 = o0 > 0.f ? o0 : __expf(o0) - 1.f;
    o1 = o1 > 0.f ? o1 : __expf(o1) - 1.f;
    o2 = o2 > 0.f ? o2 : __expf(o2) - 1.f;
    o3 = o3 > 0.f ? o3 : __expf(o3) - 1.f;
    if (half == 0)
        *(float4*)&h1[(size_t)n * 128 + c0] = make_float4(o0, o1, o2, o3);
}

__device__ __forceinline__ void edge2_step(
    const int2* __restrict__ cpack, const unsigned char* __restrict__ xr2b, int p, int l,
    const f2& xl01, const f2& xl23, const f2& We01, const f2& We23,
    const f2& at6a, const f2& at6b, const f2& at4a, const f2& at4b,
    f2& acc01, f2& acc23, float& den, bool tail, int pmax) {
    bool valid = !tail || (p <= pmax);
    int2 pk = cpack[valid ? p : pmax];
    float eav = __int_as_float(pk.y);
    unsigned off = (unsigned)pk.x * 128u + (unsigned)(l * 8);
    uint2 dw = *(const uint2*)(xr2b + off);
    f2 x01, x23;
    x01.x = bf_lo(dw.x); x01.y = bf_hi(dw.x);
    x23.x = bf_lo(dw.y); x23.y = bf_hi(dw.y);
    f2 ev = {eav, eav};
    f2 u01 = pkfma(ev, We01, xl01) + x01;
    f2 u23 = pkfma(ev, We23, xl23) + x23;
    float dot = fmaf(at6a.x, u01.x, at4a.x * fabsf(u01.x));
    dot = fmaf(at6a.y, u01.y, fmaf(at4a.y, fabsf(u01.y), dot));
    dot = fmaf(at6b.x, u23.x, fmaf(at4b.x, fabsf(u23.x), dot));
    dot = fmaf(at6b.y, u23.y, fmaf(at4b.y, fabsf(u23.y), dot));
    dot += __shfl_xor(dot, 1);
    dot += __shfl_xor(dot, 2);
    dot += __shfl_xor(dot, 4);
    dot += __shfl_xor(dot, 8);          // logit (16-lane group)
    float el = exp2f(dot);
    if (tail && !valid) el = 0.f;
    den += el;
    f2 el2 = {el, el};
    acc01 = pkfma(el2, x01, acc01);
    acc23 = pkfma(el2, x23, acc23);
}

// layer 2: wave per node; 4 edge groups x 2 slots = 8 bf16 gathers in flight; single head
__global__ __launch_bounds__(256) void k_fused2(
    const int* __restrict__ rs, const int2* __restrict__ cpack,
    const float* __restrict__ xl2, const unsigned char* __restrict__ xr2b,
    const float* __restrict__ We, const float* __restrict__ att,
    const float* __restrict__ bias, const float* __restrict__ g,
    const float* __restrict__ b, float* __restrict__ out) {
    int lane = threadIdx.x & 63;
    int n = blockIdx.x * 4 + (threadIdx.x >> 6);
    if (n >= NN) return;
    int grp = lane >> 4;
    int l = lane & 15;
    int c0 = l * 4;
    float4 xldf = *(const float4*)&xl2[(size_t)n * 64 + c0];
    float4 Wef = *(const float4*)&We[c0];
    float4 atv = *(const float4*)&att[c0];
    f2 xl01 = {xldf.x, xldf.y}, xl23 = {xldf.z, xldf.w};
    f2 We01 = {Wef.x, Wef.y}, We23 = {Wef.z, Wef.w};
    f2 at6a = {atv.x * (0.6f * LOG2E), atv.y * (0.6f * LOG2E)};
    f2 at6b = {atv.z * (0.6f * LOG2E), atv.w * (0.6f * LOG2E)};
    f2 at4a = {atv.x * (0.4f * LOG2E), atv.y * (0.4f * LOG2E)};
    f2 at4b = {atv.z * (0.4f * LOG2E), atv.w * (0.4f * LOG2E)};
    int beg = rs[n], end = rs[n + 1];
    int cnt = end - beg;
    int pfull = beg + (cnt & ~7);
    f2 a01[2] = {{0.f, 0.f}, {0.f, 0.f}};
    f2 a23[2] = {{0.f, 0.f}, {0.f, 0.f}};
    float den[2] = {0.f, 0.f};
    for (int p0 = beg; p0 < pfull; p0 += 8) {
#pragma unroll
        for (int s = 0; s < 2; ++s)
            edge2_step(cpack, xr2b, p0 + s * 4 + grp, l, xl01, xl23, We01, We23,
                       at6a, at6b, at4a, at4b, a01[s], a23[s], den[s], false, 0);
    }
    if (cnt & 7) {
#pragma unroll
        for (int s = 0; s < 2; ++s)
            edge2_step(cpack, xr2b, pfull + s * 4 + grp, l, xl01, xl23, We01, We23,
                       at6a, at6b, at4a, at4b, a01[s], a23[s], den[s], true, end - 1);
    }
    f2 s01 = a01[0] + a01[1];
    f2 s23 = a23[0] + a23[1];
    float den0 = den[0] + den[1];
    s01.x += __shfl_xor(s01.x, 16); s01.x += __shfl_xor(s01.x, 32);
    s01.y += __shfl_xor(s01.y, 16); s01.y += __shfl_xor(s01.y, 32);
    s23.x += __shfl_xor(s23.x, 16); s23.x += __shfl_xor(s23.x, 32);
    s23.y += __shfl_xor(s23.y, 16); s23.y += __shfl_xor(s23.y, 32);
    den0 += __shfl_xor(den0, 16); den0 += __shfl_xor(den0, 32);
    float inv = den0 > 0.f ? 1.f / den0 : 0.f;
    float4 bv = *(const float4*)&bias[c0];
    float a0 = s01.x * inv + bv.x;
    float a1 = s01.y * inv + bv.y;
    float a2 = s23.x * inv + bv.z;
    float a3 = s23.y * inv + bv.w;
    float mu = red16g(a0 + a1 + a2 + a3) * (1.f / 64.f);
    float d0 = a0 - mu, d1 = a1 - mu, d2 = a2 - mu, d3 = a3 - mu;
    float var = red16g(d0 * d0 + d1 * d1 + d2 * d2 + d3 * d3) * (1.f / 64.f);
    float rsq = rsqrtf(var + LNEPS);
    float4 gv = *(const float4*)&g[c0];
    float4 bb = *(const float4*)&b[c0];
    float o0 = d0 * rsq * gv.x + bb.x;
    float o1 = d1 * rsq * gv.y + bb.y;
    float o2 = d2 * rsq * gv.z + bb.z;
    float o3 = d3 * rsq * gv.w + bb.w;
    o0 = o0 > 0.f ? o0 : __expf(o0) - 1.f;
    o1 = o1 > 0.f ? o1 : __expf(o1) - 1.f;
    o2 = o2 > 0.f ? o2 : __expf(o2) - 1.f;
    o3 = o3 > 0.f ? o3 : __expf(o3) - 1.f;
    if (grp == 0)
        *(float4*)&out[(size_t)n * 64 + c0] = make_float4(o0, o1, o2, o3);
}

extern "C" void kernel_launch(void* const* d_in, const int* in_sizes, int n_in,
                              void* d_out, int out_size, void* d_ws, size_t ws_size,
                              hipStream_t stream) {
    const float* x    = (const float*)d_in[0];
    const float* ea   = (const float*)d_in[1];
    const float* W1l  = (const float*)d_in[2];
    const float* W1r  = (const float*)d_in[3];
    const float* W1e  = (const float*)d_in[4];
    const float* att1 = (const float*)d_in[5];
    const float* b1   = (const float*)d_in[6];
    const float* ln1g = (const float*)d_in[7];
    const float* ln1b = (const float*)d_in[8];
    const float* W2l  = (const float*)d_in[9];
    const float* W2r  = (const float*)d_in[10];
    const float* W2e  = (const float*)d_in[11];
    const float* att2 = (const float*)d_in[12];
    const float* b2   = (const float*)d_in[13];
    const float* ln2g = (const float*)d_in[14];
    const float* ln2b = (const float*)d_in[15];
    const int*   ei   = (const int*)d_in[16];
    float* out = (float*)d_out;
    float* ws  = (float*)d_ws;

    const size_t A = (size_t)NN * 128;
    float* xl1 = ws;                                   // N*128 f32
    float* h1  = ws + A;                               // N*128 f32
    float* xl2 = ws + 2 * A;                           // N*64 f32
    unsigned* xr1b = (unsigned*)(ws + 2 * A + (size_t)NN * 64);   // N*64 dwords (128 bf16)
    unsigned* xr2b = xr1b + (size_t)NN * 64;           // N*32 dwords (64 bf16)
    int2* cpack  = (int2*)(xr2b + (size_t)NN * 32);    // NE x 8B {src, ea}
    int2* coarse = cpack + (size_t)NE;                 // NE x 8B {src|dl<<16, ea}
    int* bh      = (int*)(coarse + (size_t)NE);        // CH_BLOCKS*256
    int* coltotal= bh + (size_t)CH_BLOCKS * 256;       // 256
    int* bb      = coltotal + 256;                     // 257
    int* rowstart= bb + 258;                           // NN+1

    k_proj1<<<(NN + 3) / 4, 256, 0, stream>>>(x, W1l, W1r, xl1, xr1b);
    k_hist<<<CH_BLOCKS, 256, 0, stream>>>(ei, bh);
    k_colscan<<<256, 256, 0, stream>>>(bh, coltotal);
    k_bb<<<1, 256, 0, stream>>>(coltotal, bb);
    k_coarse<<<CH_BLOCKS, 256, 0, stream>>>(ei, ea, bh, bb, coarse);
    k_fine<<<NBUK, 256, 0, stream>>>(coarse, bb, rowstart, cpack);

    k_fused1<<<(NN + 3) / 4, 256, 0, stream>>>(rowstart, cpack, xl1,
                                               (const unsigned char*)xr1b, W1e, att1, b1,
                                               ln1g, ln1b, h1);
    k_proj2<<<(NN + 63) / 64, 256, 0, stream>>>(h1, W2l, W2r, xl2, xr2b);
    k_fused2<<<(NN + 3) / 4, 256, 0, stream>>>(rowstart, cpack, xl2,
                                               (const unsigned char*)xr2b, W2e, att2, b2,
                                               ln2g, ln2b, out);
}

// Round 12
// 266.914 us; speedup vs baseline: 1.1201x; 1.0267x over previous
//
#include <hip/hip_runtime.h>
#include <math.h>

#define NN 50000
#define NE 800000
#define IN_CH 10
#define NEGS 0.2f
#define LNEPS 1e-5f
#define LOG2E 1.4426950408889634f
#define P1_BLOCKS 12500           // NN/4 proj1 blocks in the merged proj1+hist kernel
#define CH_BLOCKS 782             // ceil(NE / 1024) edge-chunk blocks
#define NBUK 196                  // ceil(NN / 256) coarse buckets (dst >> 8)

typedef float f2 __attribute__((ext_vector_type(2)));

__device__ __forceinline__ f2 pkfma(f2 a, f2 b, f2 c) {
    return __builtin_elementwise_fma(a, b, c);
}
__device__ __forceinline__ float red16g(float v) {   // sum within aligned 16-lane group
    v += __shfl_xor(v, 1);  v += __shfl_xor(v, 2);
    v += __shfl_xor(v, 4);  v += __shfl_xor(v, 8);
    return v;
}
__device__ __forceinline__ float red32g(float v) {   // sum within aligned 32-lane group
    v = red16g(v); v += __shfl_xor(v, 16);
    return v;
}

// bf16 pack/unpack: RTNE encode, 1-op decode (bf16 pair per dword)
__device__ __forceinline__ unsigned pack_bf16(float a, float b) {
    unsigned ua = __float_as_uint(a);
    unsigned ub = __float_as_uint(b);
    ua = (ua + 0x7FFFu + ((ua >> 16) & 1u)) >> 16;
    ub = (ub + 0x7FFFu + ((ub >> 16) & 1u)) & 0xFFFF0000u;
    return ua | ub;
}
__device__ __forceinline__ float bf_lo(unsigned d) { return __uint_as_float(d << 16); }
__device__ __forceinline__ float bf_hi(unsigned d) { return __uint_as_float(d & 0xFFFF0000u); }

// ---------- merged proj1 + hist (independent leading work, overlapped) ----------
// blocks [0, P1_BLOCKS): xl = x@W1l (f32), xrb = bf16(x@W1r)
// blocks [P1_BLOCKS, +CH_BLOCKS): per-block LDS histogram over 256 coarse buckets
__global__ __launch_bounds__(256) void k_proj1_hist(
    const float* __restrict__ x, const float* __restrict__ Wl,
    const float* __restrict__ Wr, float* __restrict__ xl, unsigned* __restrict__ xrb,
    const int* __restrict__ ei, int* __restrict__ bh) {
    __shared__ int h[256];
    int bI = blockIdx.x;
    if (bI < P1_BLOCKS) {
        int lane = threadIdx.x & 63;
        int n = bI * 4 + (threadIdx.x >> 6);
        int c0 = lane * 2;
        float al0 = 0.f, al1 = 0.f, ar0 = 0.f, ar1 = 0.f;
#pragma unroll
        for (int k = 0; k < IN_CH; ++k) {
            float xv = x[n * IN_CH + k];
            al0 = fmaf(xv, Wl[k * 128 + c0], al0);
            al1 = fmaf(xv, Wl[k * 128 + c0 + 1], al1);
            ar0 = fmaf(xv, Wr[k * 128 + c0], ar0);
            ar1 = fmaf(xv, Wr[k * 128 + c0 + 1], ar1);
        }
        *(float2*)&xl[(size_t)n * 128 + c0] = make_float2(al0, al1);
        xrb[(size_t)n * 64 + lane] = pack_bf16(ar0, ar1);
    } else {
        int t = threadIdx.x, b = bI - P1_BLOCKS;
        h[t] = 0;
        __syncthreads();
        int e0 = b * 1024 + t * 4;
        if (e0 < NE) {
            int4 d4 = *(const int4*)(ei + NE + e0);
            atomicAdd(&h[d4.x >> 8], 1);
            atomicAdd(&h[d4.y >> 8], 1);
            atomicAdd(&h[d4.z >> 8], 1);
            atomicAdd(&h[d4.w >> 8], 1);
        }
        __syncthreads();
        bh[b * 256 + t] = h[t];
    }
}

// Per-bucket column prefix over blocks (in-place) + column totals
__global__ __launch_bounds__(256) void k_colscan(
    int* __restrict__ bh, int* __restrict__ coltotal) {
    __shared__ int sh[256];
    int t = threadIdx.x, j = blockIdx.x;
    int v[4];
    int mysum = 0;
#pragma unroll
    for (int i = 0; i < 4; ++i) {
        int r = t * 4 + i;
        v[i] = (r < CH_BLOCKS) ? bh[r * 256 + j] : 0;
        mysum += v[i];
    }
    sh[t] = mysum;
    __syncthreads();
    for (int off = 1; off < 256; off <<= 1) {
        int u = (t >= off) ? sh[t - off] : 0;
        __syncthreads();
        sh[t] += u;
        __syncthreads();
    }
    int ex = sh[t] - mysum;
#pragma unroll
    for (int i = 0; i < 4; ++i) {
        int r = t * 4 + i;
        if (r < CH_BLOCKS) { bh[r * 256 + j] = ex; ex += v[i]; }
    }
    if (t == 255) coltotal[j] = sh[255];
}

// Exclusive scan of 256 bucket totals -> global bucket bases bb[257]
__global__ __launch_bounds__(256) void k_bb(
    const int* __restrict__ coltotal, int* __restrict__ bb) {
    __shared__ int sh[256];
    int t = threadIdx.x;
    int v = coltotal[t];
    sh[t] = v;
    __syncthreads();
    for (int off = 1; off < 256; off <<= 1) {
        int u = (t >= off) ? sh[t - off] : 0;
        __syncthreads();
        sh[t] += u;
        __syncthreads();
    }
    bb[t] = sh[t] - v;
    if (t == 255) bb[256] = sh[255];
}

// Scatter edges into coarse buckets; rank via returning LDS atomic
__global__ __launch_bounds__(256) void k_coarse(
    const int* __restrict__ ei, const float* __restrict__ ea,
    const int* __restrict__ bh, const int* __restrict__ bb,
    int2* __restrict__ coarse) {
    __shared__ int h[256];
    __shared__ int lbase[256];
    int t = threadIdx.x, b = blockIdx.x;
    h[t] = 0;
    lbase[t] = bb[t] + bh[b * 256 + t];
    __syncthreads();
    int e0 = b * 1024 + t * 4;
    if (e0 >= NE) return;
    int4 d4 = *(const int4*)(ei + NE + e0);
    int4 s4 = *(const int4*)(ei + e0);
    float4 a4 = *(const float4*)(ea + e0);
    {
        int bk = d4.x >> 8; int r = atomicAdd(&h[bk], 1);
        coarse[lbase[bk] + r] = make_int2(s4.x | ((d4.x & 255) << 16), __float_as_int(a4.x));
    }
    {
        int bk = d4.y >> 8; int r = atomicAdd(&h[bk], 1);
        coarse[lbase[bk] + r] = make_int2(s4.y | ((d4.y & 255) << 16), __float_as_int(a4.y));
    }
    {
        int bk = d4.z >> 8; int r = atomicAdd(&h[bk], 1);
        coarse[lbase[bk] + r] = make_int2(s4.z | ((d4.z & 255) << 16), __float_as_int(a4.z));
    }
    {
        int bk = d4.w >> 8; int r = atomicAdd(&h[bk], 1);
        coarse[lbase[bk] + r] = make_int2(s4.w | ((d4.w & 255) << 16), __float_as_int(a4.w));
    }
}

// One block per bucket — exact per-node CSR within bucket, all in LDS.
__global__ __launch_bounds__(256) void k_fine(
    const int2* __restrict__ coarse, const int* __restrict__ bb,
    int* __restrict__ rowstart, int2* __restrict__ cpack) {
    __shared__ int cnt[256];
    __shared__ int pfx[256];
    __shared__ int sh[256];
    int t = threadIdx.x, b = blockIdx.x;
    cnt[t] = 0;
    __syncthreads();
    int lo = bb[b], hi = bb[b + 1];
    int ecnt = hi - lo;
    for (int i = t; i < ecnt; i += 256) {
        int dl = (coarse[lo + i].x >> 16) & 255;
        atomicAdd(&cnt[dl], 1);
    }
    __syncthreads();
    int v = cnt[t];
    sh[t] = v;
    __syncthreads();
    for (int off = 1; off < 256; off <<= 1) {
        int u = (t >= off) ? sh[t - off] : 0;
        __syncthreads();
        sh[t] += u;
        __syncthreads();
    }
    pfx[t] = sh[t] - v;   // exclusive in-bucket prefix
    int n0 = b * 256;
    if (n0 + t < NN) rowstart[n0 + t] = lo + (sh[t] - v);
    if (b == 0 && t == 0) rowstart[NN] = NE;
    cnt[t] = 0;
    __syncthreads();
    for (int i = t; i < ecnt; i += 256) {
        int2 c = coarse[lo + i];
        int dl = (c.x >> 16) & 255;
        int r = atomicAdd(&cnt[dl], 1);
        cpack[lo + pfx[dl] + r] = make_int2(c.x & 0xFFFF, c.y);
    }
}

// ---------- xl2|xr2b = h1 @ [W2l|W2r] — LDS-tiled register-blocked fp32 GEMM ----------
__global__ __launch_bounds__(256) void k_proj2(
    const float* __restrict__ h1, const float* __restrict__ Wl,
    const float* __restrict__ Wr, float* __restrict__ xl2, unsigned* __restrict__ xr2b) {
    __shared__ float sh_h[64][36];    // +4 pad
    __shared__ float sh_w[32][128];
    int t = threadIdx.x;
    int cg = t & 15, ng = t >> 4;
    int c0 = cg * 8;
    int nb = blockIdx.x * 64;
    float acc[4][8];
#pragma unroll
    for (int j = 0; j < 4; ++j)
#pragma unroll
        for (int i = 0; i < 8; ++i) acc[j][i] = 0.f;

    for (int kc = 0; kc < 128; kc += 32) {
#pragma unroll
        for (int i = 0; i < 2; ++i) {
            int fi = t + i * 256;
            int nl = fi >> 3, kq = fi & 7;
            int n = nb + nl;
            float4 v = make_float4(0.f, 0.f, 0.f, 0.f);
            if (n < NN) v = *(const float4*)&h1[(size_t)n * 128 + kc + kq * 4];
            *(float4*)&sh_h[nl][kq * 4] = v;
        }
#pragma unroll
        for (int i = 0; i < 4; ++i) {
            int fi = t + i * 256;
            int kl = fi >> 5, col = (fi & 31) * 4;
            const float* src = (col < 64) ? &Wl[(size_t)(kc + kl) * 64 + col]
                                          : &Wr[(size_t)(kc + kl) * 64 + col - 64];
            *(float4*)&sh_w[kl][col] = *(const float4*)src;
        }
        __syncthreads();
#pragma unroll
        for (int kl = 0; kl < 32; kl += 4) {
            float4 hv[4];
#pragma unroll
            for (int j = 0; j < 4; ++j) hv[j] = *(const float4*)&sh_h[ng + j * 16][kl];
#pragma unroll
            for (int kk = 0; kk < 4; ++kk) {
                float4 wa = *(const float4*)&sh_w[kl + kk][c0];
                float4 wb = *(const float4*)&sh_w[kl + kk][c0 + 4];
#pragma unroll
                for (int j = 0; j < 4; ++j) {
                    float hs = kk == 0 ? hv[j].x : kk == 1 ? hv[j].y : kk == 2 ? hv[j].z : hv[j].w;
                    acc[j][0] = fmaf(hs, wa.x, acc[j][0]);
                    acc[j][1] = fmaf(hs, wa.y, acc[j][1]);
                    acc[j][2] = fmaf(hs, wa.z, acc[j][2]);
                    acc[j][3] = fmaf(hs, wa.w, acc[j][3]);
                    acc[j][4] = fmaf(hs, wb.x, acc[j][4]);
                    acc[j][5] = fmaf(hs, wb.y, acc[j][5]);
                    acc[j][6] = fmaf(hs, wb.z, acc[j][6]);
                    acc[j][7] = fmaf(hs, wb.w, acc[j][7]);
                }
            }
        }
        __syncthreads();
    }
    if (cg < 8) {
#pragma unroll
        for (int j = 0; j < 4; ++j) {
            int n = nb + ng + j * 16;
            if (n < NN) {
                *(float4*)&xl2[(size_t)n * 64 + c0] =
                    make_float4(acc[j][0], acc[j][1], acc[j][2], acc[j][3]);
                *(float4*)&xl2[(size_t)n * 64 + c0 + 4] =
                    make_float4(acc[j][4], acc[j][5], acc[j][6], acc[j][7]);
            }
        }
    } else {
        int cc = c0 - 64;
#pragma unroll
        for (int j = 0; j < 4; ++j) {
            int n = nb + ng + j * 16;
            if (n < NN) {
                uint4 pk;
                pk.x = pack_bf16(acc[j][0], acc[j][1]);
                pk.y = pack_bf16(acc[j][2], acc[j][3]);
                pk.z = pack_bf16(acc[j][4], acc[j][5]);
                pk.w = pack_bf16(acc[j][6], acc[j][7]);
                *(uint4*)&xr2b[(size_t)n * 32 + (cc >> 1)] = pk;
            }
        }
    }
}

// ---------- fused per-node GATv2 layers ----------
// att·lrelu(u) folded as (0.6att)·u + (0.4att)·|u| (abs = free VOP3 modifier);
// log2e folded so softmax weight = exp2(dot). Loads batched per 8/16-edge window
// (all cpack loads, then all gathers) so the compiler pipelines vmcnt waits.

// layer 1: wave per node; window of 8 edges = 4 batched gather pairs.
__global__ __launch_bounds__(256) void k_fused1(
    const int* __restrict__ rs, const int2* __restrict__ cpack,
    const float* __restrict__ xl, const unsigned char* __restrict__ xrb,
    const float* __restrict__ We, const float* __restrict__ att,
    const float* __restrict__ bias, const float* __restrict__ g,
    const float* __restrict__ b, float* __restrict__ h1) {
    int lane = threadIdx.x & 63;
    int n = blockIdx.x * 4 + (threadIdx.x >> 6);
    if (n >= NN) return;
    int half = lane >> 5;
    int l = lane & 31;
    int c0 = l * 4;
    float4 xldf = *(const float4*)&xl[(size_t)n * 128 + c0];
    float4 Wef = *(const float4*)&We[c0];
    float4 atv = *(const float4*)&att[c0];
    f2 xl01 = {xldf.x, xldf.y}, xl23 = {xldf.z, xldf.w};
    f2 We01 = {Wef.x, Wef.y}, We23 = {Wef.z, Wef.w};
    f2 at6a = {atv.x * (0.6f * LOG2E), atv.y * (0.6f * LOG2E)};
    f2 at6b = {atv.z * (0.6f * LOG2E), atv.w * (0.6f * LOG2E)};
    f2 at4a = {atv.x * (0.4f * LOG2E), atv.y * (0.4f * LOG2E)};
    f2 at4b = {atv.z * (0.4f * LOG2E), atv.w * (0.4f * LOG2E)};
    int beg = rs[n], end = rs[n + 1];
    int cnt = end - beg;
    int pfull = beg + (cnt & ~7);
    f2 a01[2] = {{0.f, 0.f}, {0.f, 0.f}};
    f2 a23[2] = {{0.f, 0.f}, {0.f, 0.f}};
    float den[2] = {0.f, 0.f};
    for (int p0 = beg; p0 < pfull; p0 += 8) {
        int2 pk[4];
#pragma unroll
        for (int s = 0; s < 4; ++s) pk[s] = cpack[p0 + s * 2 + half];
        uint2 dw[4];
#pragma unroll
        for (int s = 0; s < 4; ++s)
            dw[s] = *(const uint2*)(xrb + (unsigned)pk[s].x * 256u + (unsigned)(l * 8));
#pragma unroll
        for (int s = 0; s < 4; ++s) {
            float eav = __int_as_float(pk[s].y);
            f2 x01, x23;
            x01.x = bf_lo(dw[s].x); x01.y = bf_hi(dw[s].x);
            x23.x = bf_lo(dw[s].y); x23.y = bf_hi(dw[s].y);
            f2 ev = {eav, eav};
            f2 u01 = pkfma(ev, We01, xl01) + x01;
            f2 u23 = pkfma(ev, We23, xl23) + x23;
            float dot = fmaf(at6a.x, u01.x, at4a.x * fabsf(u01.x));
            dot = fmaf(at6a.y, u01.y, fmaf(at4a.y, fabsf(u01.y), dot));
            dot = fmaf(at6b.x, u23.x, fmaf(at4b.x, fabsf(u23.x), dot));
            dot = fmaf(at6b.y, u23.y, fmaf(at4b.y, fabsf(u23.y), dot));
            dot += __shfl_xor(dot, 1);
            dot += __shfl_xor(dot, 2);
            dot += __shfl_xor(dot, 4);      // head logit (8-lane group)
            float el = exp2f(dot);          // max-shift skipped: alpha invariant
            int w = s & 1;
            den[w] += el;
            f2 el2 = {el, el};
            a01[w] = pkfma(el2, x01, a01[w]);
            a23[w] = pkfma(el2, x23, a23[w]);
        }
    }
    if (cnt & 7) {
        int2 pk[4];
        bool vv[4];
#pragma unroll
        for (int s = 0; s < 4; ++s) {
            int p = pfull + s * 2 + half;
            vv[s] = p < end;
            pk[s] = cpack[vv[s] ? p : end - 1];
        }
        uint2 dw[4];
#pragma unroll
        for (int s = 0; s < 4; ++s)
            dw[s] = *(const uint2*)(xrb + (unsigned)pk[s].x * 256u + (unsigned)(l * 8));
#pragma unroll
        for (int s = 0; s < 4; ++s) {
            float eav = __int_as_float(pk[s].y);
            f2 x01, x23;
            x01.x = bf_lo(dw[s].x); x01.y = bf_hi(dw[s].x);
            x23.x = bf_lo(dw[s].y); x23.y = bf_hi(dw[s].y);
            f2 ev = {eav, eav};
            f2 u01 = pkfma(ev, We01, xl01) + x01;
            f2 u23 = pkfma(ev, We23, xl23) + x23;
            float dot = fmaf(at6a.x, u01.x, at4a.x * fabsf(u01.x));
            dot = fmaf(at6a.y, u01.y, fmaf(at4a.y, fabsf(u01.y), dot));
            dot = fmaf(at6b.x, u23.x, fmaf(at4b.x, fabsf(u23.x), dot));
            dot = fmaf(at6b.y, u23.y, fmaf(at4b.y, fabsf(u23.y), dot));
            dot += __shfl_xor(dot, 1);
            dot += __shfl_xor(dot, 2);
            dot += __shfl_xor(dot, 4);
            float el = vv[s] ? exp2f(dot) : 0.f;
            int w = s & 1;
            den[w] += el;
            f2 el2 = {el, el};
            a01[w] = pkfma(el2, x01, a01[w]);
            a23[w] = pkfma(el2, x23, a23[w]);
        }
    }
    f2 s01 = a01[0] + a01[1];
    f2 s23 = a23[0] + a23[1];
    float den0 = den[0] + den[1];
    s01.x += __shfl_xor(s01.x, 32);
    s01.y += __shfl_xor(s01.y, 32);
    s23.x += __shfl_xor(s23.x, 32);
    s23.y += __shfl_xor(s23.y, 32);
    den0 += __shfl_xor(den0, 32);
    float inv = den0 > 0.f ? 1.f / den0 : 0.f;
    float4 bv = *(const float4*)&bias[c0];
    float a0 = s01.x * inv + bv.x;
    float a1 = s01.y * inv + bv.y;
    float a2 = s23.x * inv + bv.z;
    float a3 = s23.y * inv + bv.w;
    float mu = red32g(a0 + a1 + a2 + a3) * (1.f / 128.f);
    float d0 = a0 - mu, d1 = a1 - mu, d2 = a2 - mu, d3 = a3 - mu;
    float var = red32g(d0 * d0 + d1 * d1 + d2 * d2 + d3 * d3) * (1.f / 128.f);
    float rsq = rsqrtf(var + LNEPS);
    float4 gv = *(const float4*)&g[c0];
    float4 bb = *(const float4*)&b[c0];
    float o0 = d0 * rsq * gv.x + bb.x;
    float o1 = d1 * rsq * gv.y + bb.y;
    float o2 = d2 * rsq * gv.z + bb.z;
    float o3 = d3 * rsq * gv.w + bb.w;
    o0 = o0 > 0.f ? o0 : __expf(o0) - 1.f;
    o1 = o1 > 0.f ? o1 : __expf(o1) - 1.f;
    o2 = o2 > 0.f ? o2 : __expf(o2) - 1.f;
    o3 = o3 > 0.f ? o3 : __expf(o3) - 1.f;
    if (half == 0)
        *(float4*)&h1[(size_t)n * 128 + c0] = make_float4(o0, o1, o2, o3);
}

// layer 2: wave per node; window of 16 edges = 4 batched gather quads; single head
__global__ __launch_bounds__(256) void k_fused2(
    const int* __restrict__ rs, const int2* __restrict__ cpack,
    const float* __restrict__ xl2, const unsigned char* __restrict__ xr2b,
    const float* __restrict__ We, const float* __restrict__ att,
    const float* __restrict__ bias, const float* __restrict__ g,
    const float* __restrict__ b, float* __restrict__ out) {
    int lane = threadIdx.x & 63;
    int n = blockIdx.x * 4 + (threadIdx.x >> 6);
    if (n >= NN) return;
    int grp = lane >> 4;
    int l = lane & 15;
    int c0 = l * 4;
    float4 xldf = *(const float4*)&xl2[(size_t)n * 64 + c0];
    float4 Wef = *(const float4*)&We[c0];
    float4 atv = *(const float4*)&att[c0];
    f2 xl01 = {xldf.x, xldf.y}, xl23 = {xldf.z, xldf.w};
    f2 We01 = {Wef.x, Wef.y}, We23 = {Wef.z, Wef.w};
    f2 at6a = {atv.x * (0.6f * LOG2E), atv.y * (0.6f * LOG2E)};
    f2 at6b = {atv.z * (0.6f * LOG2E), atv.w * (0.6f * LOG2E)};
    f2 at4a = {atv.x * (0.4f * LOG2E), atv.y * (0.4f * LOG2E)};
    f2 at4b = {atv.z * (0.4f * LOG2E), atv.w * (0.4f * LOG2E)};
    int beg = rs[n], end = rs[n + 1];
    int cnt = end - beg;
    int pfull = beg + (cnt & ~15);
    f2 a01[2] = {{0.f, 0.f}, {0.f, 0.f}};
    f2 a23[2] = {{0.f, 0.f}, {0.f, 0.f}};
    float den[2] = {0.f, 0.f};
    for (int p0 = beg; p0 < pfull; p0 += 16) {
        int2 pk[4];
#pragma unroll
        for (int s = 0; s < 4; ++s) pk[s] = cpack[p0 + s * 4 + grp];
        uint2 dw[4];
#pragma unroll
        for (int s = 0; s < 4; ++s)
            dw[s] = *(const uint2*)(xr2b + (unsigned)pk[s].x * 128u + (unsigned)(l * 8));
#pragma unroll
        for (int s = 0; s < 4; ++s) {
            float eav = __int_as_float(pk[s].y);
            f2 x01, x23;
            x01.x = bf_lo(dw[s].x); x01.y = bf_hi(dw[s].x);
            x23.x = bf_lo(dw[s].y); x23.y = bf_hi(dw[s].y);
            f2 ev = {eav, eav};
            f2 u01 = pkfma(ev, We01, xl01) + x01;
            f2 u23 = pkfma(ev, We23, xl23) + x23;
            float dot = fmaf(at6a.x, u01.x, at4a.x * fabsf(u01.x));
            dot = fmaf(at6a.y, u01.y, fmaf(at4a.y, fabsf(u01.y), dot));
            dot = fmaf(at6b.x, u23.x, fmaf(at4b.x, fabsf(u23.x), dot));
            dot = fmaf(at6b.y, u23.y, fmaf(at4b.y, fabsf(u23.y), dot));
            dot += __shfl_xor(dot, 1);
            dot += __shfl_xor(dot, 2);
            dot += __shfl_xor(dot, 4);
            dot += __shfl_xor(dot, 8);      // logit (16-lane group)
            float el = exp2f(dot);
            int w = s & 1;
            den[w] += el;
            f2 el2 = {el, el};
            a01[w] = pkfma(el2, x01, a01[w]);
            a23[w] = pkfma(el2, x23, a23[w]);
        }
    }
    if (cnt & 15) {
        int2 pk[4];
        bool vv[4];
#pragma unroll
        for (int s = 0; s < 4; ++s) {
            int p = pfull + s * 4 + grp;
            vv[s] = p < end;
            pk[s] = cpack[vv[s] ? p : end - 1];
        }
        uint2 dw[4];
#pragma unroll
        for (int s = 0; s < 4; ++s)
            dw[s] = *(const uint2*)(xr2b + (unsigned)pk[s].x * 128u + (unsigned)(l * 8));
#pragma unroll
        for (int s = 0; s < 4; ++s) {
            float eav = __int_as_float(pk[s].y);
            f2 x01, x23;
            x01.x = bf_lo(dw[s].x); x01.y = bf_hi(dw[s].x);
            x23.x = bf_lo(dw[s].y); x23.y = bf_hi(dw[s].y);
            f2 ev = {eav, eav};
            f2 u01 = pkfma(ev, We01, xl01) + x01;
            f2 u23 = pkfma(ev, We23, xl23) + x23;
            float dot = fmaf(at6a.x, u01.x, at4a.x * fabsf(u01.x));
            dot = fmaf(at6a.y, u01.y, fmaf(at4a.y, fabsf(u01.y), dot));
            dot = fmaf(at6b.x, u23.x, fmaf(at4b.x, fabsf(u23.x), dot));
            dot = fmaf(at6b.y, u23.y, fmaf(at4b.y, fabsf(u23.y), dot));
            dot += __shfl_xor(dot, 1);
            dot += __shfl_xor(dot, 2);
            dot += __shfl_xor(dot, 4);
            dot += __shfl_xor(dot, 8);
            float el = vv[s] ? exp2f(dot) : 0.f;
            int w = s & 1;
            den[w] += el;
            f2 el2 = {el, el};
            a01[w] = pkfma(el2, x01, a01[w]);
            a23[w] = pkfma(el2, x23, a23[w]);
        }
    }
    f2 s01 = a01[0] + a01[1];
    f2 s23 = a23[0] + a23[1];
    float den0 = den[0] + den[1];
    s01.x += __shfl_xor(s01.x, 16); s01.x += __shfl_xor(s01.x, 32);
    s01.y += __shfl_xor(s01.y, 16); s01.y += __shfl_xor(s01.y, 32);
    s23.x += __shfl_xor(s23.x, 16); s23.x += __shfl_xor(s23.x, 32);
    s23.y += __shfl_xor(s23.y, 16); s23.y += __shfl_xor(s23.y, 32);
    den0 += __shfl_xor(den0, 16); den0 += __shfl_xor(den0, 32);
    float inv = den0 > 0.f ? 1.f / den0 : 0.f;
    float4 bv = *(const float4*)&bias[c0];
    float a0 = s01.x * inv + bv.x;
    float a1 = s01.y * inv + bv.y;
    float a2 = s23.x * inv + bv.z;
    float a3 = s23.y * inv + bv.w;
    float mu = red16g(a0 + a1 + a2 + a3) * (1.f / 64.f);
    float d0 = a0 - mu, d1 = a1 - mu, d2 = a2 - mu, d3 = a3 - mu;
    float var = red16g(d0 * d0 + d1 * d1 + d2 * d2 + d3 * d3) * (1.f / 64.f);
    float rsq = rsqrtf(var + LNEPS);
    float4 gv = *(const float4*)&g[c0];
    float4 bb = *(const float4*)&b[c0];
    float o0 = d0 * rsq * gv.x + bb.x;
    float o1 = d1 * rsq * gv.y + bb.y;
    float o2 = d2 * rsq * gv.z + bb.z;
    float o3 = d3 * rsq * gv.w + bb.w;
    o0 = o0 > 0.f ? o0 : __expf(o0) - 1.f;
    o1 = o1 > 0.f ? o1 : __expf(o1) - 1.f;
    o2 = o2 > 0.f ? o2 : __expf(o2) - 1.f;
    o3 = o3 > 0.f ? o3 : __expf(o3) - 1.f;
    if (grp == 0)
        *(float4*)&out[(size_t)n * 64 + c0] = make_float4(o0, o1, o2, o3);
}

extern "C" void kernel_launch(void* const* d_in, const int* in_sizes, int n_in,
                              void* d_out, int out_size, void* d_ws, size_t ws_size,
                              hipStream_t stream) {
    const float* x    = (const float*)d_in[0];
    const float* ea   = (const float*)d_in[1];
    const float* W1l  = (const float*)d_in[2];
    const float* W1r  = (const float*)d_in[3];
    const float* W1e  = (const float*)d_in[4];
    const float* att1 = (const float*)d_in[5];
    const float* b1   = (const float*)d_in[6];
    const float* ln1g = (const float*)d_in[7];
    const float* ln1b = (const float*)d_in[8];
    const float* W2l  = (const float*)d_in[9];
    const float* W2r  = (const float*)d_in[10];
    const float* W2e  = (const float*)d_in[11];
    const float* att2 = (const float*)d_in[12];
    const float* b2   = (const float*)d_in[13];
    const float* ln2g = (const float*)d_in[14];
    const float* ln2b = (const float*)d_in[15];
    const int*   ei   = (const int*)d_in[16];
    float* out = (float*)d_out;
    float* ws  = (float*)d_ws;

    const size_t A = (size_t)NN * 128;
    float* xl1 = ws;                                   // N*128 f32
    float* h1  = ws + A;                               // N*128 f32
    float* xl2 = ws + 2 * A;                           // N*64 f32
    unsigned* xr1b = (unsigned*)(ws + 2 * A + (size_t)NN * 64);   // N*64 dwords (128 bf16)
    unsigned* xr2b = xr1b + (size_t)NN * 64;           // N*32 dwords (64 bf16)
    int2* cpack  = (int2*)(xr2b + (size_t)NN * 32);    // NE x 8B {src, ea}
    int2* coarse = cpack + (size_t)NE;                 // NE x 8B {src|dl<<16, ea}
    int* bh      = (int*)(coarse + (size_t)NE);        // CH_BLOCKS*256
    int* coltotal= bh + (size_t)CH_BLOCKS * 256;       // 256
    int* bb      = coltotal + 256;                     // 257
    int* rowstart= bb + 258;                           // NN+1

    k_proj1_hist<<<P1_BLOCKS + CH_BLOCKS, 256, 0, stream>>>(x, W1l, W1r, xl1, xr1b,
                                                            ei, bh);
    k_colscan<<<256, 256, 0, stream>>>(bh, coltotal);
    k_bb<<<1, 256, 0, stream>>>(coltotal, bb);
    k_coarse<<<CH_BLOCKS, 256, 0, stream>>>(ei, ea, bh, bb, coarse);
    k_fine<<<NBUK, 256, 0, stream>>>(coarse, bb, rowstart, cpack);

    k_fused1<<<(NN + 3) / 4, 256, 0, stream>>>(rowstart, cpack, xl1,
                                               (const unsigned char*)xr1b, W1e, att1, b1,
                                               ln1g, ln1b, h1);
    k_proj2<<<(NN + 63) / 64, 256, 0, stream>>>(h1, W2l, W2r, xl2, xr2b);
    k_fused2<<<(NN + 3) / 4, 256, 0, stream>>>(rowstart, cpack, xl2,
                                               (const unsigned char*)xr2b, W2e, att2, b2,
                                               ln2g, ln2b, out);
}